// Round 5
// baseline (92.676 us; speedup 1.0000x reference)
//
#include <hip/hip_runtime.h>
#include <math.h>

// out[n,o] = exp(A)*cos(B)
//   A = sum_i ln(R)*Wr - K*Wi ;  B = sum_i ln(R)*Wi + K*Wr
//   R = 1 + g*(|x|-1) = fma(|x|, g, 1-g),  K = pi*(x<0)*g,  g = clip(G,0,1)
// n=8192, i=o=128.
//
// R5: R3/R4 were LDS-PIPE bound (per-CU shared resource): every wave's
// broadcast ds_read_b128 of the x-planes cost ~12cy of CU LDS BW -> ~41us
// floor at R3 geometry. Fix: x is wave-uniform per (row,i) -> read it with
// s_load (scalar pipe) straight from global. q = readfirstlane(tid>>7) makes
// the address provably uniform. Inner body/elem: R-fma (SGPR |x|), v_log,
// 2x2 acc-FMAs (SGPR ps) - zero LDS, zero vector x-loads. Geometry: RPB=8,
// NT=512 (o:128 x q:4 i-quarters), 1024 blocks x 8 waves = 8192 waves =
// 8/SIMD; LDS only for epilogue q-reduce (32KB -> 4 blocks/CU).
// VALU floor ~8.5us, trans ~6.8us.

#define NROWS 8192
#define DIM   128
#define RPB   8
#define NT    512
#define IQ    32          // i's per quarter
#define PI_F  3.14159265358979323846f
#define LN2_F 0.69314718055994530942f

typedef float v2f __attribute__((ext_vector_type(2)));

// wq[i*DIM+o] = (ln2*wr, ln2*wi, -g*wi, g*wr); gq = (g, 1-g). One-time.
__global__ __launch_bounds__(256) void prep_w(
    const float* __restrict__ Wr, const float* __restrict__ Wi,
    const float* __restrict__ G, float4* __restrict__ wq,
    float2* __restrict__ gq)
{
    int t = blockIdx.x * 256 + threadIdx.x;
    if (t < DIM * DIM) {
        float g  = fminf(fmaxf(G[t], 0.0f), 1.0f);
        float wr = Wr[t], wi = Wi[t];
        wq[t] = make_float4(LN2_F * wr, LN2_F * wi, -g * wi, g * wr);
        gq[t] = make_float2(g, 1.0f - g);
    }
}

template <bool PACKED>
__global__ __launch_bounds__(NT, 8) void main_kernel(
    const float* __restrict__ x, const float4* __restrict__ wq,
    const float2* __restrict__ gq,
    const float* __restrict__ Wr, const float* __restrict__ Wi,
    const float* __restrict__ G, float* __restrict__ out)
{
    // LDS only for the epilogue reduce: pA/pB [4][RPB][DIM] = 32 KB.
    __shared__ float sbuf[2 * 4 * RPB * DIM];

    const int tid   = threadIdx.x;
    const int o     = tid & (DIM - 1);
    const int q     = __builtin_amdgcn_readfirstlane(tid >> 7);  // wave-uniform
    const int nbase = blockIdx.x * RPB;
    const int ibase = q * IQ;

    // Uniform base: all x reads below are scalar (s_load), batched by unroll.
    const float* xb = x + (size_t)nbase * DIM + ibase;

    float accA[RPB], accB[RPB];
#pragma unroll
    for (int r = 0; r < RPB; ++r) { accA[r] = 0.0f; accB[r] = 0.0f; }

#pragma unroll 4
    for (int ii = 0; ii < IQ; ++ii) {
        const int i = ibase + ii;
        float wrl, wil, ngwi, gwr, g, onemg;
        if (PACKED) {
            float4 w  = wq[i * DIM + o];
            float2 g2 = gq[i * DIM + o];
            wrl = w.x; wil = w.y; ngwi = w.z; gwr = w.w;
            g = g2.x; onemg = g2.y;
        } else {
            float wr = Wr[i * DIM + o], wi = Wi[i * DIM + o];
            g = fminf(fmaxf(G[i * DIM + o], 0.0f), 1.0f);
            onemg = 1.0f - g;
            wrl = LN2_F * wr; wil = LN2_F * wi; ngwi = -g * wi; gwr = g * wr;
        }
#pragma unroll
        for (int r = 0; r < RPB; ++r) {
            float xv = xb[r * DIM + ii];          // uniform -> s_load
            float ax = fabsf(xv);                 // scalar
            float ps = (xv < 0.0f) ? PI_F : 0.0f; // scalar select
            float t  = fmaf(ax, g, onemg);        // v_fma, 1 SGPR src
            float l  = __log2f(t);                // v_log_f32
            accA[r] = fmaf(l, wrl, fmaf(ps, ngwi, accA[r]));
            accB[r] = fmaf(l, wil, fmaf(ps, gwr,  accB[r]));
        }
    }

    // Reduce partials across the 4 i-quarters via LDS (one-shot).
    float* pA = sbuf;                    // [4][RPB][DIM]
    float* pB = sbuf + 4 * RPB * DIM;
#pragma unroll
    for (int r = 0; r < RPB; ++r) {
        pA[q * (RPB * DIM) + r * DIM + o] = accA[r];
        pB[q * (RPB * DIM) + r * DIM + o] = accB[r];
    }
    __syncthreads();

    // Each thread finishes 2 consecutive (r,o) cells; float2 coalesced store.
    const int c = tid * 2;
    const int r = c >> 7, oo = c & (DIM - 1);
    v2f A = {0.f, 0.f}, B = {0.f, 0.f};
#pragma unroll
    for (int qq = 0; qq < 4; ++qq) {
        A += *(const v2f*)&pA[qq * (RPB * DIM) + r * DIM + oo];
        B += *(const v2f*)&pB[qq * (RPB * DIM) + r * DIM + oo];
    }
    float2 res;
    res.x = __expf(A.x) * __cosf(B.x);
    res.y = __expf(A.y) * __cosf(B.y);
    *(float2*)&out[(size_t)(nbase + r) * DIM + oo] = res;
}

extern "C" void kernel_launch(void* const* d_in, const int* in_sizes, int n_in,
                              void* d_out, int out_size, void* d_ws, size_t ws_size,
                              hipStream_t stream) {
    const float* x  = (const float*)d_in[0];
    const float* Wr = (const float*)d_in[1];
    const float* Wi = (const float*)d_in[2];
    const float* G  = (const float*)d_in[3];
    float* out = (float*)d_out;

    const size_t wq_bytes = (size_t)DIM * DIM * sizeof(float4);   // 256 KB
    const size_t gq_bytes = (size_t)DIM * DIM * sizeof(float2);   // 128 KB
    if (ws_size >= wq_bytes + gq_bytes) {
        float4* wq = (float4*)d_ws;
        float2* gq = (float2*)((char*)d_ws + wq_bytes);
        prep_w<<<(DIM * DIM + 255) / 256, 256, 0, stream>>>(Wr, Wi, G, wq, gq);
        main_kernel<true><<<NROWS / RPB, NT, 0, stream>>>(x, wq, gq,
                                                          nullptr, nullptr, nullptr, out);
    } else {
        main_kernel<false><<<NROWS / RPB, NT, 0, stream>>>(x, nullptr, nullptr,
                                                           Wr, Wi, G, out);
    }
}

// Round 6
// 85.440 us; speedup vs baseline: 1.0847x; 1.0847x over previous
//
#include <hip/hip_runtime.h>
#include <math.h>

// out[n,o] = exp(A)*cos(B)
//   A = sum_i ln(R)*Wr - K*Wi ;  B = sum_i ln(R)*Wi + K*Wr
//   R = 1 + g*(|x|-1) = fma(|x|-1, g, 1),  K = pi*(x<0)*g,  g = clip(G,0,1)
// n=8192, i=o=128. Floor: 134M v_log @ 1/4 rate = 6.8us; VALU ~4.3us.
//
// R6: R3 shape (RPB=8, NT=512 = o:128 x q:4 i-quarters, x via LDS broadcast
// ds_read_b128 -- R5 proved s_load regresses: SMEM out-of-order returns force
// lgkmcnt(0) drains). Changes vs R3:
//  (a) LDS 32->16KB: epilogue reduces A then reuses the buffer for B.
//  (b) __launch_bounds__(512,8): <=64 VGPR so 4 blocks/CU x 8 waves = 8/SIMD.
//  (c) one b128 weight load/iter: (ln2*wr, ln2*wi, g, g/ln2); derive
//      -g*wi = -(g/ln2)*wil, g*wr = (g/ln2)*wrl with 2 muls.

#define NROWS 8192
#define DIM   128
#define RPB   8
#define NT    512
#define IQ    32
#define PI_F  3.14159265358979323846f
#define LN2_F 0.69314718055994530942f

typedef float v2f __attribute__((ext_vector_type(2)));

static __device__ __forceinline__ v2f vfma2(v2f a, v2f b, v2f c) {
    return __builtin_elementwise_fma(a, b, c);
}

// wq[i*DIM+o] = (ln2*wr, ln2*wi, g, g/ln2). One-time, 64 blocks.
__global__ __launch_bounds__(256) void prep_w(
    const float* __restrict__ Wr, const float* __restrict__ Wi,
    const float* __restrict__ G, float4* __restrict__ wq)
{
    int t = blockIdx.x * 256 + threadIdx.x;
    if (t < DIM * DIM) {
        float g  = fminf(fmaxf(G[t], 0.0f), 1.0f);
        wq[t] = make_float4(LN2_F * Wr[t], LN2_F * Wi[t], g, g * (1.0f / LN2_F));
    }
}

template <bool PACKED>
__global__ __launch_bounds__(NT, 8) void main_kernel(
    const float* __restrict__ x, const float4* __restrict__ wq,
    const float* __restrict__ Wr, const float* __restrict__ Wi,
    const float* __restrict__ G, float* __restrict__ out)
{
    // 16 KB. Main loop: am1 plane [DIM][RPB] + ps plane [DIM][RPB] (8 KB).
    // Epilogue overlay: one partial buffer [4][RPB][DIM] (16 KB), used
    // twice (A then B).
    __shared__ float sbuf[4 * RPB * DIM];
    float* am1p = sbuf;               // [DIM][RPB]
    float* psp  = sbuf + DIM * RPB;   // [DIM][RPB]

    const int tid   = threadIdx.x;
    const int o     = tid & (DIM - 1);
    const int q     = tid >> 7;            // i-quarter 0..3
    const int nbase = blockIdx.x * RPB;
    const float* xb = x + (size_t)nbase * DIM;

    // Stage x tile (1024 floats): float2 coalesced read, SoA scatter.
    {
        float2 v = ((const float2*)xb)[tid];
        int e = tid * 2;
        int i = e & (DIM - 1), r = e >> 7;
        am1p[i * RPB + r]       = fabsf(v.x) - 1.0f;
        am1p[(i + 1) * RPB + r] = fabsf(v.y) - 1.0f;
        psp[i * RPB + r]        = (v.x < 0.0f) ? PI_F : 0.0f;
        psp[(i + 1) * RPB + r]  = (v.y < 0.0f) ? PI_F : 0.0f;
    }
    __syncthreads();

    v2f accA[4], accB[4];
#pragma unroll
    for (int p = 0; p < 4; ++p) { accA[p] = (v2f){0.f, 0.f}; accB[p] = (v2f){0.f, 0.f}; }

    const int ibase = q * IQ;
#pragma unroll 2
    for (int ii = 0; ii < IQ; ++ii) {
        const int i = ibase + ii;
        float wrl, wil, g, gq;
        if (PACKED) {
            float4 w = wq[i * DIM + o];
            wrl = w.x; wil = w.y; g = w.z; gq = w.w;
        } else {
            g   = fminf(fmaxf(G[i * DIM + o], 0.0f), 1.0f);
            wrl = LN2_F * Wr[i * DIM + o];
            wil = LN2_F * Wi[i * DIM + o];
            gq  = g * (1.0f / LN2_F);
        }
        const float ngwi = -gq * wil;     // == -g*wi
        const float gwr  =  gq * wrl;     // ==  g*wr
        const v2f gg2   = {g, g};
        const v2f wrl2  = {wrl, wrl};
        const v2f wil2  = {wil, wil};
        const v2f ngwi2 = {ngwi, ngwi};
        const v2f gwr2  = {gwr, gwr};
        const v2f one2  = {1.0f, 1.0f};

        // 8 rows via 2+2 broadcast ds_read_b128 (all lanes same address).
        const float4* a4 = (const float4*)(am1p + i * RPB);
        const float4* p4 = (const float4*)(psp  + i * RPB);
        float4 a03 = a4[0], a47 = a4[1];
        float4 s03 = p4[0], s47 = p4[1];

#define ROWPAIR(mx, my, sx, sy, idx)                                        \
        do {                                                                \
            v2f t2 = vfma2((v2f){mx, my}, gg2, one2);                       \
            v2f l2 = { __log2f(t2.x), __log2f(t2.y) };                      \
            v2f s2 = {sx, sy};                                              \
            accA[idx] = vfma2(l2, wrl2, vfma2(s2, ngwi2, accA[idx]));       \
            accB[idx] = vfma2(l2, wil2, vfma2(s2, gwr2,  accB[idx]));       \
        } while (0)

        ROWPAIR(a03.x, a03.y, s03.x, s03.y, 0);
        ROWPAIR(a03.z, a03.w, s03.z, s03.w, 1);
        ROWPAIR(a47.x, a47.y, s47.x, s47.y, 2);
        ROWPAIR(a47.z, a47.w, s47.z, s47.w, 3);
#undef ROWPAIR
    }

    // Epilogue: q-reduce via one 16 KB buffer, A then B (planes dead now).
    float* pP = sbuf;                        // [4][RPB][DIM]
    const int c = tid * 2;
    const int r = c >> 7, oo = c & (DIM - 1);

    __syncthreads();   // all waves done reading planes
#pragma unroll
    for (int p = 0; p < 4; ++p) {
        pP[q * (RPB * DIM) + (2 * p) * DIM + o]     = accA[p].x;
        pP[q * (RPB * DIM) + (2 * p + 1) * DIM + o] = accA[p].y;
    }
    __syncthreads();
    v2f A = {0.f, 0.f};
#pragma unroll
    for (int qq = 0; qq < 4; ++qq)
        A += *(const v2f*)&pP[qq * (RPB * DIM) + r * DIM + oo];
    __syncthreads();   // before overwriting with B partials
#pragma unroll
    for (int p = 0; p < 4; ++p) {
        pP[q * (RPB * DIM) + (2 * p) * DIM + o]     = accB[p].x;
        pP[q * (RPB * DIM) + (2 * p + 1) * DIM + o] = accB[p].y;
    }
    __syncthreads();
    v2f B = {0.f, 0.f};
#pragma unroll
    for (int qq = 0; qq < 4; ++qq)
        B += *(const v2f*)&pP[qq * (RPB * DIM) + r * DIM + oo];

    float2 res;
    res.x = __expf(A.x) * __cosf(B.x);
    res.y = __expf(A.y) * __cosf(B.y);
    *(float2*)&out[(size_t)(nbase + r) * DIM + oo] = res;
}

extern "C" void kernel_launch(void* const* d_in, const int* in_sizes, int n_in,
                              void* d_out, int out_size, void* d_ws, size_t ws_size,
                              hipStream_t stream) {
    const float* x  = (const float*)d_in[0];
    const float* Wr = (const float*)d_in[1];
    const float* Wi = (const float*)d_in[2];
    const float* G  = (const float*)d_in[3];
    float* out = (float*)d_out;

    const size_t wq_bytes = (size_t)DIM * DIM * sizeof(float4);   // 256 KB
    if (ws_size >= wq_bytes) {
        float4* wq = (float4*)d_ws;
        prep_w<<<(DIM * DIM + 255) / 256, 256, 0, stream>>>(Wr, Wi, G, wq);
        main_kernel<true><<<NROWS / RPB, NT, 0, stream>>>(x, wq,
                                                          nullptr, nullptr, nullptr, out);
    } else {
        main_kernel<false><<<NROWS / RPB, NT, 0, stream>>>(x, nullptr,
                                                           Wr, Wi, G, out);
    }
}